// Round 1
// baseline (150.351 us; speedup 1.0000x reference)
//
#include <hip/hip_runtime.h>

#define NB 32
#define HH 512
#define WW 512
#define WS 11
#define RAD 5
#define TX 256
#define YB 32
#define NR (YB + 2*RAD)              // 42 input rows per strip
#define XCHUNKS (WW / TX)            // 2
#define YSTRIPS (HH / YB)            // 16
#define NBLK (NB * XCHUNKS * YSTRIPS) // 1024

__global__ __launch_bounds__(256, 4)
void ssim_main(const float* __restrict__ pred,
               const float* __restrict__ targ,
               const float* __restrict__ win,
               float* __restrict__ partial)
{
    __shared__ float2 rowbuf[2][TX + 2*RAD];   // 2 x 266 x 8B = 4.3 KB

    const int tid = threadIdx.x;
    const int bid = blockIdx.x;
    const int chunk  = bid & (XCHUNKS - 1);
    const int t2     = bid >> 1;
    const int ystrip = t2 & (YSTRIPS - 1);
    const int img    = t2 >> 4;

    const int x0 = chunk * TX;
    const int y0 = ystrip * YB;
    const int x  = x0 + tid;

    // 1D gaussian from window row 5: w[5][i] = g5*g[i], g5 = sqrt(w[5][5])
    float g[WS];
    {
        const float inv = rsqrtf(win[5*WS + 5]);
        #pragma unroll
        for (int i = 0; i < WS; ++i) g[i] = win[5*WS + i] * inv;
    }

    const float* __restrict__ pimg = pred + (size_t)img * (HH*WW);
    const float* __restrict__ timg = targ + (size_t)img * (HH*WW);

    // ring buffers: horizontal conv results for 11 rows x 5 fields (static idx only)
    float rp[WS], rt[WS], rpp[WS], rtt[WS], rpt[WS];

    float pm, tm, ph, th;        // current row staged in regs
    float npm, ntm, nph, nth;    // prefetched next row

    auto fetch = [&](int r, float& a, float& b, float& c, float& d) {
        const int yin = y0 - RAD + r;
        a = 0.f; b = 0.f; c = 0.f; d = 0.f;
        if (yin >= 0 && yin < HH) {
            const float* prow = pimg + yin * WW;
            const float* trow = timg + yin * WW;
            a = prow[x];
            b = trow[x];
            if (tid < 2*RAD) {
                const int l = (tid < RAD) ? tid : (tid + TX);
                const int col = x0 - RAD + l;
                if (col >= 0 && col < WW) { c = prow[col]; d = trow[col]; }
            }
        }
    };

    fetch(0, pm, tm, ph, th);

    float acc = 0.f;
    const float C1 = 1.0e-4f, C2 = 9.0e-4f;

    #pragma unroll 1
    for (int rb = 0; rb < (NR + WS - 1) / WS; ++rb) {
        #pragma unroll
        for (int j = 0; j < WS; ++j) {
            const int r = rb * WS + j;     // ring slot = r % 11 = j (static)
            if (r < NR) {
                const int par = r & 1;
                // stage current row into LDS (packed p,t)
                rowbuf[par][tid + RAD] = make_float2(pm, tm);
                if (tid < 2*RAD) {
                    const int l = (tid < RAD) ? tid : (tid + TX);
                    rowbuf[par][l] = make_float2(ph, th);
                }
                // prefetch next row while this one is consumed
                if (r + 1 < NR) fetch(r + 1, npm, ntm, nph, nth);
                __syncthreads();

                // horizontal conv of 5 fields into ring slot j
                {
                    float sp = 0.f, st = 0.f, spp = 0.f, stt = 0.f, spt = 0.f;
                    #pragma unroll
                    for (int k = 0; k < WS; ++k) {
                        const float2 v = rowbuf[par][tid + k];
                        const float gk = g[k];
                        const float gp = gk * v.x;
                        const float gt = gk * v.y;
                        sp += gp;
                        st += gt;
                        spp = fmaf(gp, v.x, spp);
                        stt = fmaf(gt, v.y, stt);
                        spt = fmaf(gp, v.y, spt);
                    }
                    rp[j] = sp; rt[j] = st; rpp[j] = spp; rtt[j] = stt; rpt[j] = spt;
                }

                // vertical conv + SSIM for output row y0 + r - 10
                if (r >= 2*RAD) {
                    float mu1 = 0.f, mu2 = 0.f, cpp = 0.f, ctt = 0.f, cpt = 0.f;
                    #pragma unroll
                    for (int k = 0; k < WS; ++k) {
                        const int s = (j + 1 + k) % WS;   // static after unroll
                        const float gk = g[k];
                        mu1 = fmaf(gk, rp[s],  mu1);
                        mu2 = fmaf(gk, rt[s],  mu2);
                        cpp = fmaf(gk, rpp[s], cpp);
                        ctt = fmaf(gk, rtt[s], ctt);
                        cpt = fmaf(gk, rpt[s], cpt);
                    }
                    const float m11 = mu1 * mu1;
                    const float m22 = mu2 * mu2;
                    const float m12 = mu1 * mu2;
                    const float s1  = cpp - m11;
                    const float s2  = ctt - m22;
                    const float s12 = cpt - m12;
                    const float num = (2.f*m12 + C1) * (2.f*s12 + C2);
                    const float den = (m11 + m22 + C1) * (s1 + s2 + C2);
                    acc += __fdividef(num, den);
                }
                pm = npm; tm = ntm; ph = nph; th = nth;
            }
        }
    }

    // block reduction -> one partial per block (deterministic, no atomics)
    #pragma unroll
    for (int off = 32; off > 0; off >>= 1)
        acc += __shfl_down(acc, off, 64);
    __shared__ float red[4];
    if ((tid & 63) == 0) red[tid >> 6] = acc;
    __syncthreads();
    if (tid == 0) partial[bid] = red[0] + red[1] + red[2] + red[3];
}

__global__ void ssim_final(const float* __restrict__ partial, float* __restrict__ out)
{
    const int tid = threadIdx.x;
    float v = partial[tid] + partial[tid + 256] + partial[tid + 512] + partial[tid + 768];
    #pragma unroll
    for (int off = 32; off > 0; off >>= 1)
        v += __shfl_down(v, off, 64);
    __shared__ float red[4];
    if ((tid & 63) == 0) red[tid >> 6] = v;
    __syncthreads();
    if (tid == 0)
        out[0] = 1.f - (red[0] + red[1] + red[2] + red[3]) / (float)(NB * HH * WW);
}

extern "C" void kernel_launch(void* const* d_in, const int* in_sizes, int n_in,
                              void* d_out, int out_size, void* d_ws, size_t ws_size,
                              hipStream_t stream) {
    const float* pred = (const float*)d_in[0];
    const float* targ = (const float*)d_in[1];
    const float* win  = (const float*)d_in[2];
    float* out = (float*)d_out;
    float* partial = (float*)d_ws;   // NBLK floats = 4 KB

    ssim_main<<<NBLK, 256, 0, stream>>>(pred, targ, win, partial);
    ssim_final<<<1, 256, 0, stream>>>(partial, out);
}